// Round 14
// baseline (232.256 us; speedup 1.0000x reference)
//
#include <hip/hip_runtime.h>
#include <hip/hip_bf16.h>

#define DGRID 128
#define E1 127
#define E2 125
#define E3 123

typedef __attribute__((ext_vector_type(8))) short short8;
typedef __attribute__((ext_vector_type(4))) float f32x4;

static __device__ __forceinline__ unsigned short f2bf(float f) {
    union { __hip_bfloat16 h; unsigned short u; } cv;
    cv.h = __float2bfloat16(f);
    return cv.u;
}

// ---------------- stage 0: zero dense grid (4-ch padded) ----------------
__global__ __launch_bounds__(256) void zero_k(float4* __restrict__ p, int n4) {
    int i = blockIdx.x * 256 + threadIdx.x;
    if (i < n4) p[i] = make_float4(0.f, 0.f, 0.f, 0.f);
}

// ---------------- stage 1: scatter voxels into dense grid ----------------
__global__ __launch_bounds__(256) void scatter_k(const int* __restrict__ coords,
                                                 const float* __restrict__ voxels,
                                                 float* __restrict__ dense, int N) {
    int i = blockIdx.x * blockDim.x + threadIdx.x;
    if (i >= N * 3) return;
    int n = i / 3, c = i - n * 3;
    int b = coords[n * 4 + 0];
    int z = coords[n * 4 + 1];
    int y = coords[n * 4 + 2];
    int x = coords[n * 4 + 3];
    int idx = (((b * DGRID + z) * DGRID + y) * DGRID + x) * 4 + c;   // 4-ch padded
    atomicAdd(&dense[idx], voxels[n * 3 + c]);
}

// ---------------- stage 1b: compose W12 = conv1 o conv2 (4x4x4 x 3ci x 5co, fp32) ----------------
__global__ __launch_bounds__(256) void wcomp_k(const float* __restrict__ W1f,
                                               const float* __restrict__ W2f,
                                               float* __restrict__ W12) {
    for (int e = threadIdx.x; e < 960; e += 256) {
        const int tap = e / 15, r = e % 15;
        const int ci = r / 5, co = r % 5;
        const int KZ = tap >> 4, KY = (tap >> 2) & 3, KX = tap & 3;
        float acc = 0.f;
#pragma unroll
        for (int k1z = 0; k1z < 2; ++k1z) {
            const int k2z = KZ - k1z;
            if (k2z < 0 || k2z > 2) continue;
#pragma unroll
            for (int k1y = 0; k1y < 2; ++k1y) {
                const int k2y = KY - k1y;
                if (k2y < 0 || k2y > 2) continue;
#pragma unroll
                for (int k1x = 0; k1x < 2; ++k1x) {
                    const int k2x = KX - k1x;
                    if (k2x < 0 || k2x > 2) continue;
                    const float* w1 = W1f + ((k1z * 2 + k1y) * 2 + k1x) * 27 + ci * 9;
                    const float* w2 = W2f + ((k2z * 3 + k2y) * 3 + k2x) * 45 + co;
#pragma unroll
                    for (int m = 0; m < 9; ++m) acc += w1[m] * w2[m * 5];
                }
            }
        }
        W12[tap * 15 + r] = acc;
    }
}

// ---------------- stage 2: composed conv1+conv2 as ONE direct 4^3 conv (bf16 MFMA) ----------------
// Dense halo 11x11x19 bf16 4-ch records (8B) in LDS, PLUS a copy shifted by one record
// so any (s, s+1) pair is a single aligned ds_read_b128. 8 mfma per 16 outputs.
// Loop interchange: 4 batches x (8 taps x 4 groups); group offsets fold to ds imm offsets.
__global__ __launch_bounds__(256, 4) void conv12_k(const float* __restrict__ dense,
                                                   const float* __restrict__ W12,
                                                   short* __restrict__ x2s) {
    __shared__ __align__(16) char sDD[38720];   // [0,19360): recs @ (z*11+y)*160 + x*8
                                                // [19360,38720): rec r at slot r-1

    const int tid = threadIdx.x;
    int blk = blockIdx.x;
    const int xt  = blk & 7;  blk >>= 3;
    const int tyt = blk & 15; blk >>= 4;
    const int tzt = blk & 15; blk >>= 4;
    const int b   = blk;
    const int z0 = tzt * 8, y0 = tyt * 8, x0 = xt * 16;

    const int lane = tid & 63;
    const int col  = lane & 15;
    const int q4   = lane >> 4;          // 0..3
    const int wv   = tid >> 6;

    // ---- B-fragments from W12: tap = 8t + 2*q4 + (j>>2), ci = j&3
    short8 B12[8];
#pragma unroll
    for (int t = 0; t < 8; ++t) {
#pragma unroll
        for (int j = 0; j < 8; ++j) {
            const int tap = 8 * t + 2 * q4 + (j >> 2);
            const int ci  = j & 3;
            float v = (ci < 3 && col < 5) ? W12[tap * 15 + ci * 5 + col] : 0.f;
            B12[t][j] = (short)f2bf(v);
        }
    }

    // ---- loop-invariant per-t read offsets (row part + x part + parity buffer select)
    int ofs[8];
#pragma unroll
    for (int t = 0; t < 8; ++t) {
        const int T0 = 8 * t + 2 * q4;
        const int kz = T0 >> 4, ky = (T0 >> 2) & 3, kx0 = T0 & 3;   // kx0 in {0,2}
        const int s = col + kx0;
        ofs[t] = (kz * 11 + ky) * 160 + ((s & 1) ? (19360 + (s - 1) * 8) : (s * 8));
    }

    // ---- stage dense halo: 11z * 11y * 19x records (float4 -> bf16x4, 8B) + shifted copy
#pragma unroll 1
    for (int p = tid; p < 2299; p += 256) {
        const int xp = p % 19; int t2 = p / 19;
        const int yp = t2 % 11; const int zp = t2 / 11;
        const int gz = min(z0 + zp, DGRID - 1);
        const int gy = min(y0 + yp, DGRID - 1);
        const int gx = min(x0 + xp, DGRID - 1);
        const float4 v = *(const float4*)(dense +
            (size_t)(((b * DGRID + gz) * DGRID + gy) * DGRID + gx) * 4);
        const unsigned lo = (unsigned)f2bf(v.x) | ((unsigned)f2bf(v.y) << 16);
        const unsigned hi = (unsigned)f2bf(v.z) | ((unsigned)f2bf(v.w) << 16);
        const int off = (zp * 11 + yp) * 160 + xp * 8;
        *(uint2*)(sDD + off) = make_uint2(lo, hi);
        if (xp > 0) *(uint2*)(sDD + 19360 + off - 8) = make_uint2(lo, hi);
    }
    __syncthreads();

    // ---- MFMA: 4 batches x (8 t x 4 groups); acc[4] accumulates over t
#pragma unroll 1
    for (int batch = 0; batch < 4; ++batch) {
        const int zp = wv * 2 + (batch >> 1);
        const int yb = (batch & 1) * 4;
        const int rowb = (zp * 11 + yb) * 160;
        f32x4 acc[4];
#pragma unroll
        for (int i = 0; i < 4; ++i) acc[i] = (f32x4){0.f, 0.f, 0.f, 0.f};
#pragma unroll
        for (int t = 0; t < 8; ++t) {
            const char* pa = sDD + rowb + ofs[t];
#pragma unroll
            for (int i = 0; i < 4; ++i) {
                const short8 a = *(const short8*)(pa + i * 160);
                acc[i] = __builtin_amdgcn_mfma_f32_16x16x32_bf16(a, B12[t], acc[i], 0, 0, 0);
            }
        }
        // epilogue: x2 bf16 records; cols 5..7 exact zeros (B12 zero)
        const int oz = z0 + zp;
#pragma unroll
        for (int i = 0; i < 4; ++i) {
            const int oy = y0 + yb + i;
            if (oz < E2 && oy < E2 && col < 8) {
                short* op = x2s + (size_t)(((b * E2 + oz) * E2 + oy) * E2 + x0) * 8 +
                            q4 * 32 + col;
#pragma unroll
                for (int jj = 0; jj < 4; ++jj)
                    if (x0 + q4 * 4 + jj < E2) op[jj * 8] = (short)f2bf(acc[i][jj]);
            }
        }
    }
}

// ---------------- stage 3: conv3 + bias + relu via MFMA ----------------
// x2 halo 10x10x18 bf16 8-ch records in LDS, 336B row pitch (no swizzle; odd dword
// pitch rotates banks). Loop interchange: 2 batches x (7 taps x 8 groups), ds imm offsets.
__global__ __launch_bounds__(256, 4) void conv3_k(const short* __restrict__ x2s,
                                                  const float* __restrict__ W3f,
                                                  const float* __restrict__ b3f,
                                                  float* __restrict__ out) {
    __shared__ __align__(16) char sX2[33600];   // 100 rows * 336B (21 slots x 16B)

    const int tid = threadIdx.x;
    int blk = blockIdx.x;
    const int xt  = blk & 7;  blk >>= 3;
    const int tyt = blk & 15; blk >>= 4;
    const int tzt = blk & 15; blk >>= 4;
    const int b   = blk;
    const int z0 = tzt * 8, y0 = tyt * 8, x0 = xt * 16;

    // ---- stage x2 halo tile: 10z * 10y * 18x records (16B each)
#pragma unroll 1
    for (int p = tid; p < 1800; p += 256) {
        const int xp = p % 18; int t2 = p / 18;
        const int yp = t2 % 10; const int zp = t2 / 10;
        const int iz = min(z0 + zp, E2 - 1);
        const int iy = min(y0 + yp, E2 - 1);
        const int ix = min(x0 + xp, E2 - 1);
        const short8 rec = *(const short8*)(x2s + (size_t)(((b * E2 + iz) * E2 + iy) * E2 + ix) * 8);
        *(short8*)(sX2 + (zp * 10 + yp) * 336 + xp * 16) = rec;
    }

    // ---- conv3 B-fragments: k' = tap*8+ci (27 taps + 1 pad), col = out-ch (3 used)
    const int lane = tid & 63;
    const int col  = lane & 15;
    const int q4   = lane >> 4;
    short8 B3[7];
    int tdelta[7];
#pragma unroll
    for (int t = 0; t < 7; ++t) {
        const int tap = 4 * t + q4;          // k' = 32t + q4*8 + j -> tap = 4t+q4, ci = j
#pragma unroll
        for (int j = 0; j < 8; ++j) {
            float v = 0.f;
            if (tap < 27 && j < 5 && col < 3) v = W3f[(tap * 5 + j) * 3 + col];
            B3[t][j] = (short)f2bf(v);
        }
        const int tc = (tap > 26) ? 26 : tap;
        const int kz = tc / 9, ky = (tc / 3) % 3, kx = tc % 3;
        tdelta[t] = (kz * 10 + ky) * 336 + kx * 16;
    }
    const float bias = (col < 3) ? b3f[col] : 0.f;
    __syncthreads();

    // ---- MFMA: 2 batches x (7 t x 8 groups); acc[8] accumulates over t
    const int wv = tid >> 6;
#pragma unroll 1
    for (int batch = 0; batch < 2; ++batch) {
        const int zp = wv * 2 + batch;
        const int rowb = (zp * 10) * 336 + col * 16;
        f32x4 acc[8];
#pragma unroll
        for (int i = 0; i < 8; ++i) acc[i] = (f32x4){0.f, 0.f, 0.f, 0.f};
#pragma unroll
        for (int t = 0; t < 7; ++t) {
            const char* pa = sX2 + rowb + tdelta[t];
#pragma unroll
            for (int i = 0; i < 8; ++i) {
                const short8 a = *(const short8*)(pa + i * 336);
                acc[i] = __builtin_amdgcn_mfma_f32_16x16x32_bf16(a, B3[t], acc[i], 0, 0, 0);
            }
        }
        // epilogue
        const int oz = z0 + zp;
#pragma unroll
        for (int i = 0; i < 8; ++i) {
            const int oy = y0 + i;
            if (oz < E3 && oy < E3 && col < 3) {
                float* op = out + (size_t)(((b * E3 + oz) * E3 + oy) * E3 + x0) * 3 +
                            q4 * 12 + col;
#pragma unroll
                for (int jj = 0; jj < 4; ++jj)
                    if (x0 + q4 * 4 + jj < E3) op[jj * 3] = fmaxf(acc[i][jj] + bias, 0.f);
            }
        }
    }
}

extern "C" void kernel_launch(void* const* d_in, const int* in_sizes, int n_in,
                              void* d_out, int out_size, void* d_ws, size_t ws_size,
                              hipStream_t stream) {
    const int*   coords = (const int*)d_in[0];
    const float* voxels = (const float*)d_in[1];
    const float* W1     = (const float*)d_in[2];
    const float* W2     = (const float*)d_in[3];
    const float* W3     = (const float*)d_in[4];
    const float* b3     = (const float*)d_in[5];
    float* out = (float*)d_out;

    const int N = in_sizes[0] / 4;  // 100000

    // workspace: dense 4-ch fp32 (67.1 MB) + x2 bf16 8-ch (62.5 MB) + W12 (3.84 KB)
    char* ws = (char*)d_ws;
    const size_t dense_elems = (size_t)2 * DGRID * DGRID * DGRID * 4;
    const size_t dense_bytes = dense_elems * sizeof(float);
    const size_t x2_bytes    = (size_t)2 * E2 * E2 * E2 * 8 * sizeof(short);
    float* dense = (float*)ws;
    short* x2s   = (short*)(ws + dense_bytes);
    float* W12   = (float*)(ws + dense_bytes + x2_bytes);

    const int n4 = (int)(dense_elems / 4);
    zero_k<<<(n4 + 255) / 256, 256, 0, stream>>>((float4*)dense, n4);

    scatter_k<<<(N * 3 + 255) / 256, 256, 0, stream>>>(coords, voxels, dense, N);

    wcomp_k<<<1, 256, 0, stream>>>(W1, W2, W12);

    // conv12: B * z-tiles(16 of 8) * y-tiles(16 of 8) * x-tiles(8 of 16)
    const int nblk12 = 2 * 16 * 16 * 8;
    conv12_k<<<nblk12, 256, 0, stream>>>(dense, W12, x2s);

    // conv3: B * z-tiles(16 of 8) * y-tiles(16 of 8) * x-tiles(8 of 16)
    const int nblk3 = 2 * 16 * 16 * 8;
    conv3_k<<<nblk3, 256, 0, stream>>>(x2s, W3, b3, out);
}

// Round 15
// 213.357 us; speedup vs baseline: 1.0886x; 1.0886x over previous
//
#include <hip/hip_runtime.h>
#include <hip/hip_bf16.h>

#define DGRID 128
#define E1 127
#define E2 125
#define E3 123

typedef __attribute__((ext_vector_type(8))) short short8;
typedef __attribute__((ext_vector_type(4))) float f32x4;
typedef __attribute__((ext_vector_type(4))) unsigned int u32x4;

static __device__ __forceinline__ unsigned short f2bf(float f) {
    union { __hip_bfloat16 h; unsigned short u; } cv;
    cv.h = __float2bfloat16(f);
    return cv.u;
}

// ---------------- stage 0: zero dense grid + compose W12 (fused, one launch) ----------------
// Block 0: W12[KZ][KY][KX][ci][co] = sum_{k1+k2=K} sum_m W1[k1][ci][m] * W2[k2][m][co]
// Blocks 1..: zero the 4-ch padded dense grid.
__global__ __launch_bounds__(256) void zerow_k(float4* __restrict__ p, int n4,
                                               const float* __restrict__ W1f,
                                               const float* __restrict__ W2f,
                                               float* __restrict__ W12) {
    if (blockIdx.x == 0) {
        for (int e = threadIdx.x; e < 960; e += 256) {
            const int tap = e / 15, r = e % 15;
            const int ci = r / 5, co = r % 5;
            const int KZ = tap >> 4, KY = (tap >> 2) & 3, KX = tap & 3;
            float acc = 0.f;
#pragma unroll
            for (int k1z = 0; k1z < 2; ++k1z) {
                const int k2z = KZ - k1z;
                if (k2z < 0 || k2z > 2) continue;
#pragma unroll
                for (int k1y = 0; k1y < 2; ++k1y) {
                    const int k2y = KY - k1y;
                    if (k2y < 0 || k2y > 2) continue;
#pragma unroll
                    for (int k1x = 0; k1x < 2; ++k1x) {
                        const int k2x = KX - k1x;
                        if (k2x < 0 || k2x > 2) continue;
                        const float* w1 = W1f + ((k1z * 2 + k1y) * 2 + k1x) * 27 + ci * 9;
                        const float* w2 = W2f + ((k2z * 3 + k2y) * 3 + k2x) * 45 + co;
#pragma unroll
                        for (int m = 0; m < 9; ++m) acc += w1[m] * w2[m * 5];
                    }
                }
            }
            W12[tap * 15 + r] = acc;
        }
        return;
    }
    const int i = (blockIdx.x - 1) * 256 + threadIdx.x;
    if (i < n4) p[i] = make_float4(0.f, 0.f, 0.f, 0.f);
}

// ---------------- stage 1: scatter voxels into dense grid ----------------
__global__ __launch_bounds__(256) void scatter_k(const int* __restrict__ coords,
                                                 const float* __restrict__ voxels,
                                                 float* __restrict__ dense, int N) {
    int i = blockIdx.x * blockDim.x + threadIdx.x;
    if (i >= N * 3) return;
    int n = i / 3, c = i - n * 3;
    int b = coords[n * 4 + 0];
    int z = coords[n * 4 + 1];
    int y = coords[n * 4 + 2];
    int x = coords[n * 4 + 3];
    int idx = (((b * DGRID + z) * DGRID + y) * DGRID + x) * 4 + c;   // 4-ch padded
    atomicAdd(&dense[idx], voxels[n * 3 + c]);
}

// ---------------- stage 2: composed conv1+conv2 as ONE direct 4^3 conv (bf16 MFMA) ----------------
// Dense halo 11x11x19 bf16 4-ch records (8B) in LDS, 152B row pitch (19 slots; 38 dwords
// == 6 mod 32 rotates banks per row). Per MFMA: two aligned ds_read_b64 (union) — each
// quarter's 16 lanes read 128B contiguous => one address per bank per quarter.
// Loop interchange: 4 batches x (8 taps x 4 groups); hoisted ofs[t]; 8 mfma per 16 outputs.
__global__ __launch_bounds__(256, 4) void conv12_k(const float* __restrict__ dense,
                                                   const float* __restrict__ W12,
                                                   short* __restrict__ x2s) {
    __shared__ __align__(16) char sDD[18392];   // 121 rows * 152B

    const int tid = threadIdx.x;
    int blk = blockIdx.x;
    const int xt  = blk & 7;  blk >>= 3;
    const int tyt = blk & 15; blk >>= 4;
    const int tzt = blk & 15; blk >>= 4;
    const int b   = blk;
    const int z0 = tzt * 8, y0 = tyt * 8, x0 = xt * 16;

    const int lane = tid & 63;
    const int col  = lane & 15;
    const int q4   = lane >> 4;          // 0..3
    const int wv   = tid >> 6;

    // ---- B-fragments from W12: tap = 8t + 2*q4 + (j>>2), ci = j&3
    short8 B12[8];
#pragma unroll
    for (int t = 0; t < 8; ++t) {
#pragma unroll
        for (int j = 0; j < 8; ++j) {
            const int tap = 8 * t + 2 * q4 + (j >> 2);
            const int ci  = j & 3;
            float v = (ci < 3 && col < 5) ? W12[tap * 15 + ci * 5 + col] : 0.f;
            B12[t][j] = (short)f2bf(v);
        }
    }

    // ---- loop-invariant per-t read offsets
    int ofs[8];
#pragma unroll
    for (int t = 0; t < 8; ++t) {
        const int T0 = 8 * t + 2 * q4;
        const int kz = T0 >> 4, ky = (T0 >> 2) & 3, kx0 = T0 & 3;   // kx0 in {0,2}
        ofs[t] = (kz * 11 + ky) * 152 + (col + kx0) * 8;
    }

    // ---- stage dense halo: 11z * 11y * 19x records (float4 -> bf16x4, 8B)
#pragma unroll 1
    for (int p = tid; p < 2299; p += 256) {
        const int xp = p % 19; int t2 = p / 19;
        const int yp = t2 % 11; const int zp = t2 / 11;
        const int gz = min(z0 + zp, DGRID - 1);
        const int gy = min(y0 + yp, DGRID - 1);
        const int gx = min(x0 + xp, DGRID - 1);
        const float4 v = *(const float4*)(dense +
            (size_t)(((b * DGRID + gz) * DGRID + gy) * DGRID + gx) * 4);
        const unsigned lo = (unsigned)f2bf(v.x) | ((unsigned)f2bf(v.y) << 16);
        const unsigned hi = (unsigned)f2bf(v.z) | ((unsigned)f2bf(v.w) << 16);
        *(uint2*)(sDD + (zp * 11 + yp) * 152 + xp * 8) = make_uint2(lo, hi);
    }
    __syncthreads();

    // ---- MFMA: 4 batches x (8 t x 4 groups); acc[4] accumulates over t
#pragma unroll 1
    for (int batch = 0; batch < 4; ++batch) {
        const int zp = wv * 2 + (batch >> 1);
        const int yb = (batch & 1) * 4;
        const int rowb = (zp * 11 + yb) * 152;
        f32x4 acc[4];
#pragma unroll
        for (int i = 0; i < 4; ++i) acc[i] = (f32x4){0.f, 0.f, 0.f, 0.f};
#pragma unroll
        for (int t = 0; t < 8; ++t) {
            const char* pa = sDD + rowb + ofs[t];
#pragma unroll
            for (int i = 0; i < 4; ++i) {
                const uint2 ra = *(const uint2*)(pa + i * 152);
                const uint2 rb = *(const uint2*)(pa + i * 152 + 8);
                union { u32x4 u; short8 s; } av;
                av.u[0] = ra.x; av.u[1] = ra.y; av.u[2] = rb.x; av.u[3] = rb.y;
                acc[i] = __builtin_amdgcn_mfma_f32_16x16x32_bf16(av.s, B12[t], acc[i], 0, 0, 0);
            }
        }
        // epilogue: x2 bf16 records; cols 5..7 exact zeros (B12 zero)
        const int oz = z0 + zp;
#pragma unroll
        for (int i = 0; i < 4; ++i) {
            const int oy = y0 + yb + i;
            if (oz < E2 && oy < E2 && col < 8) {
                short* op = x2s + (size_t)(((b * E2 + oz) * E2 + oy) * E2 + x0) * 8 +
                            q4 * 32 + col;
#pragma unroll
                for (int jj = 0; jj < 4; ++jj)
                    if (x0 + q4 * 4 + jj < E2) op[jj * 8] = (short)f2bf(acc[i][jj]);
            }
        }
    }
}

// ---------------- stage 3: conv3 + bias + relu via MFMA (r14 form, proven) ----------------
__global__ __launch_bounds__(256, 4) void conv3_k(const short* __restrict__ x2s,
                                                  const float* __restrict__ W3f,
                                                  const float* __restrict__ b3f,
                                                  float* __restrict__ out) {
    __shared__ __align__(16) char sX2[33600];   // 100 rows * 336B (21 slots x 16B)

    const int tid = threadIdx.x;
    int blk = blockIdx.x;
    const int xt  = blk & 7;  blk >>= 3;
    const int tyt = blk & 15; blk >>= 4;
    const int tzt = blk & 15; blk >>= 4;
    const int b   = blk;
    const int z0 = tzt * 8, y0 = tyt * 8, x0 = xt * 16;

    // ---- stage x2 halo tile: 10z * 10y * 18x records (16B each)
#pragma unroll 1
    for (int p = tid; p < 1800; p += 256) {
        const int xp = p % 18; int t2 = p / 18;
        const int yp = t2 % 10; const int zp = t2 / 10;
        const int iz = min(z0 + zp, E2 - 1);
        const int iy = min(y0 + yp, E2 - 1);
        const int ix = min(x0 + xp, E2 - 1);
        const short8 rec = *(const short8*)(x2s + (size_t)(((b * E2 + iz) * E2 + iy) * E2 + ix) * 8);
        *(short8*)(sX2 + (zp * 10 + yp) * 336 + xp * 16) = rec;
    }

    // ---- conv3 B-fragments: k' = tap*8+ci (27 taps + 1 pad), col = out-ch (3 used)
    const int lane = tid & 63;
    const int col  = lane & 15;
    const int q4   = lane >> 4;
    short8 B3[7];
    int tdelta[7];
#pragma unroll
    for (int t = 0; t < 7; ++t) {
        const int tap = 4 * t + q4;          // k' = 32t + q4*8 + j -> tap = 4t+q4, ci = j
#pragma unroll
        for (int j = 0; j < 8; ++j) {
            float v = 0.f;
            if (tap < 27 && j < 5 && col < 3) v = W3f[(tap * 5 + j) * 3 + col];
            B3[t][j] = (short)f2bf(v);
        }
        const int tc = (tap > 26) ? 26 : tap;
        const int kz = tc / 9, ky = (tc / 3) % 3, kx = tc % 3;
        tdelta[t] = (kz * 10 + ky) * 336 + kx * 16;
    }
    const float bias = (col < 3) ? b3f[col] : 0.f;
    __syncthreads();

    // ---- MFMA: 2 batches x (7 t x 8 groups); acc[8] accumulates over t
    const int wv = tid >> 6;
#pragma unroll 1
    for (int batch = 0; batch < 2; ++batch) {
        const int zp = wv * 2 + batch;
        const int rowb = (zp * 10) * 336 + col * 16;
        f32x4 acc[8];
#pragma unroll
        for (int i = 0; i < 8; ++i) acc[i] = (f32x4){0.f, 0.f, 0.f, 0.f};
#pragma unroll
        for (int t = 0; t < 7; ++t) {
            const char* pa = sX2 + rowb + tdelta[t];
#pragma unroll
            for (int i = 0; i < 8; ++i) {
                const short8 a = *(const short8*)(pa + i * 336);
                acc[i] = __builtin_amdgcn_mfma_f32_16x16x32_bf16(a, B3[t], acc[i], 0, 0, 0);
            }
        }
        // epilogue
        const int oz = z0 + zp;
#pragma unroll
        for (int i = 0; i < 8; ++i) {
            const int oy = y0 + i;
            if (oz < E3 && oy < E3 && col < 3) {
                float* op = out + (size_t)(((b * E3 + oz) * E3 + oy) * E3 + x0) * 3 +
                            q4 * 12 + col;
#pragma unroll
                for (int jj = 0; jj < 4; ++jj)
                    if (x0 + q4 * 4 + jj < E3) op[jj * 3] = fmaxf(acc[i][jj] + bias, 0.f);
            }
        }
    }
}

extern "C" void kernel_launch(void* const* d_in, const int* in_sizes, int n_in,
                              void* d_out, int out_size, void* d_ws, size_t ws_size,
                              hipStream_t stream) {
    const int*   coords = (const int*)d_in[0];
    const float* voxels = (const float*)d_in[1];
    const float* W1     = (const float*)d_in[2];
    const float* W2     = (const float*)d_in[3];
    const float* W3     = (const float*)d_in[4];
    const float* b3     = (const float*)d_in[5];
    float* out = (float*)d_out;

    const int N = in_sizes[0] / 4;  // 100000

    // workspace: dense 4-ch fp32 (67.1 MB) + x2 bf16 8-ch (62.5 MB) + W12 (3.84 KB)
    char* ws = (char*)d_ws;
    const size_t dense_elems = (size_t)2 * DGRID * DGRID * DGRID * 4;
    const size_t dense_bytes = dense_elems * sizeof(float);
    const size_t x2_bytes    = (size_t)2 * E2 * E2 * E2 * 8 * sizeof(short);
    float* dense = (float*)ws;
    short* x2s   = (short*)(ws + dense_bytes);
    float* W12   = (float*)(ws + dense_bytes + x2_bytes);

    // fused zero + wcomp (block 0 = wcomp, rest zero dense)
    const int n4 = (int)(dense_elems / 4);
    zerow_k<<<(n4 + 255) / 256 + 1, 256, 0, stream>>>((float4*)dense, n4, W1, W2, W12);

    scatter_k<<<(N * 3 + 255) / 256, 256, 0, stream>>>(coords, voxels, dense, N);

    // conv12: B * z-tiles(16 of 8) * y-tiles(16 of 8) * x-tiles(8 of 16)
    const int nblk12 = 2 * 16 * 16 * 8;
    conv12_k<<<nblk12, 256, 0, stream>>>(dense, W12, x2s);

    // conv3: B * z-tiles(16 of 8) * y-tiles(16 of 8) * x-tiles(8 of 16)
    const int nblk3 = 2 * 16 * 16 * 8;
    conv3_k<<<nblk3, 256, 0, stream>>>(x2s, W3, b3, out);
}